// Round 6
// baseline (176.164 us; speedup 1.0000x reference)
//
#include <hip/hip_runtime.h>
#include <hip/hip_bf16.h>

#define SEQ 4096
#define CDIM 512
#define NHEAD 8
#define HDIM 64
#define KVB 64
#define NSPLIT 4
#define TILES_PER_SPLIT (SEQ / KVB / NSPLIT)   // 16

typedef __attribute__((ext_vector_type(8))) short bf16x8;
typedef __attribute__((ext_vector_type(4))) float f32x4;
typedef __attribute__((ext_vector_type(16))) float f32x16;

__device__ __forceinline__ short f2b(float f) {
  union { float f; unsigned u; } v; v.f = f;
  unsigned u = v.u;
  unsigned r = u + 0x7fffu + ((u >> 16) & 1u);
  return (short)(r >> 16);
}
__device__ __forceinline__ float b2f(short s) {
  union { unsigned u; float f; } v; v.u = ((unsigned)(unsigned short)s) << 16;
  return v.f;
}
__device__ __forceinline__ unsigned pk2(float a, float b) {
  union { __hip_bfloat162 h; unsigned u; } z;
  z.h = __float22bfloat162_rn(make_float2(a, b));
  return z.u;
}

// ---- prep: fp32->bf16 convert of x (blocks 0..2047) + 4 weight transposes ----
__global__ __launch_bounds__(256) void prep_kernel(
    const float* __restrict__ x,
    const float* __restrict__ Wq, const float* __restrict__ Wk,
    const float* __restrict__ Wv, const float* __restrict__ Wo,
    short* __restrict__ xb,
    short* __restrict__ Wqt, short* __restrict__ Wkt,
    short* __restrict__ Wvt, short* __restrict__ Wot) {
  __shared__ short tile[32][33];
  int b = blockIdx.x, tid = threadIdx.x;
  if (b < 2048) {
    int i = (b * 256 + tid) * 4;
    float4 v = *(const float4*)(x + i);
    short4 o;
    o.x = f2b(v.x); o.y = f2b(v.y); o.z = f2b(v.z); o.w = f2b(v.w);
    *(short4*)(xb + i) = o;
    return;
  }
  int t = b - 2048;
  int mat = t >> 8; t &= 255;
  const float* W = mat == 0 ? Wq : mat == 1 ? Wk : mat == 2 ? Wv : Wo;
  short* Wt = mat == 0 ? Wqt : mat == 1 ? Wkt : mat == 2 ? Wvt : Wot;
  int n0 = (t & 15) * 32, k0 = (t >> 4) * 32;
  int tx = tid & 31, ty = tid >> 5;  // 32 x 8
  for (int i = 0; i < 32; i += 8)
    tile[ty + i][tx] = f2b(W[(size_t)(k0 + ty + i) * CDIM + n0 + tx]);
  __syncthreads();
  for (int i = 0; i < 32; i += 8)
    Wt[(size_t)(n0 + ty + i) * CDIM + k0 + tx] = tile[tx][ty + i];
}

// ---- fused QKV GEMM: z=0 -> Q (bf16 [M][N]), z=1 -> K, z=2 -> V transposed [N][M] ----
__global__ __launch_bounds__(256) void qkv_gemm_kernel(
    const short* __restrict__ A,
    const short* __restrict__ Wqt, const short* __restrict__ Wkt, const short* __restrict__ Wvt,
    const float* __restrict__ bq, const float* __restrict__ bk, const float* __restrict__ bv,
    short* __restrict__ Qb, short* __restrict__ Kb, short* __restrict__ Vtb) {
  __shared__ short As[64 * 64];
  __shared__ short Bs[64 * 64];
  const int z = blockIdx.z;
  const short* Bt = z == 0 ? Wqt : z == 1 ? Wkt : Wvt;
  const float* bias = z == 0 ? bq : z == 1 ? bk : bv;
  const int m0 = blockIdx.x * 64, n0 = blockIdx.y * 64;
  const int tid = threadIdx.x;
  const int w = tid >> 6, lane = tid & 63, g = lane >> 4, l16 = lane & 15;
  f32x4 acc[4] = {};
  for (int kt = 0; kt < CDIM; kt += 64) {
    __syncthreads();
    for (int it = 0; it < 2; ++it) {
      int c = tid + it * 256;
      int r = c >> 3, cc = (c & 7) * 8;
      int sw = r * 64 + (cc ^ ((r & 7) * 8));
      *(bf16x8*)(As + sw) = *(const bf16x8*)(A + (size_t)(m0 + r) * CDIM + kt + cc);
      *(bf16x8*)(Bs + sw) = *(const bf16x8*)(Bt + (size_t)(n0 + r) * CDIM + kt + cc);
    }
    __syncthreads();
    const int ar = w * 16 + l16;
    for (int ks = 0; ks < 2; ++ks) {
      int c0 = ks * 32 + 8 * g;
      bf16x8 af = *(const bf16x8*)(As + ar * 64 + (c0 ^ ((ar & 7) * 8)));
      for (int ni = 0; ni < 4; ++ni) {
        int br = ni * 16 + l16;
        bf16x8 bf = *(const bf16x8*)(Bs + br * 64 + (c0 ^ ((br & 7) * 8)));
        acc[ni] = __builtin_amdgcn_mfma_f32_16x16x32_bf16(af, bf, acc[ni], 0, 0, 0);
      }
    }
  }
  for (int ni = 0; ni < 4; ++ni) {
    int col = n0 + ni * 16 + l16;
    float bv_ = bias[col];
    for (int j = 0; j < 4; ++j) {
      int row = m0 + w * 16 + g * 4 + j;
      float v = acc[ni][j] + bv_;
      if (z == 0)      Qb[(size_t)row * CDIM + col] = f2b(v);
      else if (z == 1) Kb[(size_t)row * CDIM + col] = f2b(v);
      else             Vtb[(size_t)col * SEQ + row] = f2b(v);
    }
  }
}

// ---- output projection GEMM: fp32 out ----
__global__ __launch_bounds__(256) void out_gemm_kernel(
    const short* __restrict__ A, const short* __restrict__ Bt,
    const float* __restrict__ bias, float* __restrict__ out) {
  __shared__ short As[64 * 64];
  __shared__ short Bs[64 * 64];
  const int m0 = blockIdx.x * 64, n0 = blockIdx.y * 64;
  const int tid = threadIdx.x;
  const int w = tid >> 6, lane = tid & 63, g = lane >> 4, l16 = lane & 15;
  f32x4 acc[4] = {};
  for (int kt = 0; kt < CDIM; kt += 64) {
    __syncthreads();
    for (int it = 0; it < 2; ++it) {
      int c = tid + it * 256;
      int r = c >> 3, cc = (c & 7) * 8;
      int sw = r * 64 + (cc ^ ((r & 7) * 8));
      *(bf16x8*)(As + sw) = *(const bf16x8*)(A + (size_t)(m0 + r) * CDIM + kt + cc);
      *(bf16x8*)(Bs + sw) = *(const bf16x8*)(Bt + (size_t)(n0 + r) * CDIM + kt + cc);
    }
    __syncthreads();
    const int ar = w * 16 + l16;
    for (int ks = 0; ks < 2; ++ks) {
      int c0 = ks * 32 + 8 * g;
      bf16x8 af = *(const bf16x8*)(As + ar * 64 + (c0 ^ ((ar & 7) * 8)));
      for (int ni = 0; ni < 4; ++ni) {
        int br = ni * 16 + l16;
        bf16x8 bf = *(const bf16x8*)(Bs + br * 64 + (c0 ^ ((br & 7) * 8)));
        acc[ni] = __builtin_amdgcn_mfma_f32_16x16x32_bf16(af, bf, acc[ni], 0, 0, 0);
      }
    }
  }
  for (int ni = 0; ni < 4; ++ni) {
    int col = n0 + ni * 16 + l16;
    float bv_ = bias[col];
    for (int j = 0; j < 4; ++j) {
      int row = m0 + w * 16 + g * 4 + j;
      out[(size_t)row * CDIM + col] = acc[ni][j] + bv_;
    }
  }
}

// ---- flash attention partials. Grid: 32 qtiles x 8 heads x 4 kv-splits = 1024
// blocks, 512 threads = 8 waves = 4 rh (32 q each, q-tile 128) x 2 kq (32 kv).
// KVB=64, K/V double-buffered via global_load_lds; 1 barrier/iter.
// No-max softmax -> partials additive: each block writes unnormalized bf16
// O-partial + f32 l-partial; combine_kernel sums the 4 splits.
__global__ __launch_bounds__(512, 8) void attn_kernel(
    const short* __restrict__ Qb,   // [SEQ][CDIM] bf16
    const short* __restrict__ Kb,   // [SEQ][CDIM] bf16
    const short* __restrict__ Vtb,  // [CDIM][SEQ] bf16 (d-major)
    short* __restrict__ Op0, short* __restrict__ Op1,
    short* __restrict__ Op2, short* __restrict__ Op3,
    float* __restrict__ lpart) {    // [NSPLIT][NHEAD][SEQ]
  __shared__ __align__(16) char arena[33792];   // Ks[2][4096] + Vs[2][4096]; epi: bufA[4*64*33] f32
  __shared__ float lzp[4][32];
  short* KsB = (short*)arena;
  short* VsB = (short*)(arena + 16384);
  const int bid = blockIdx.x;
  const int h = bid & 7;                 // head ~ XCD
  const int rest = bid >> 3;
  const int split = rest & 3;
  const int q0 = (rest >> 2) * 128;
  const int kvbase = split * (TILES_PER_SPLIT * KVB);
  const int tid = threadIdx.x;
  const int wid = tid >> 6, lane = tid & 63;
  const int l31 = lane & 31, hi = lane >> 5;
  const int rh = wid >> 1, kq = wid & 1;
  const float scale2 = 0.06375872274f;   // (1/sqrt(512)) * log2(e)

  short* Opart = split == 0 ? Op0 : split == 1 ? Op1 : split == 2 ? Op2 : Op3;

  // Q in B-frag layout (n=q=lane&31, k-slices of d), pre-scaled
  bf16x8 qf[4];
  {
    int qrow = q0 + rh * 32 + l31;
#pragma unroll
    for (int kst = 0; kst < 4; ++kst) {
      bf16x8 q = *(const bf16x8*)(Qb + (size_t)qrow * CDIM + h * 64 + kst * 16 + hi * 8);
#pragma unroll
      for (int i = 0; i < 8; ++i) q[i] = f2b(b2f(q[i]) * scale2);
      qf[kst] = q;
    }
  }

  // glds staging: linear LDS dest (tid*16B), inverse-swizzled global source col
  const int srow = tid >> 3;                       // 0..63 (K: kv row; V: d row)
  const int scol8 = 8 * ((tid & 7) ^ (srow & 7));
  auto stage = [&](int buf, int kv0) {
    __builtin_amdgcn_global_load_lds(
        (const __attribute__((address_space(1))) void*)(
            Kb + (size_t)(kv0 + srow) * CDIM + h * 64 + scol8),
        (__attribute__((address_space(3))) void*)(&KsB[buf * 4096 + tid * 8]), 16, 0, 0);
    __builtin_amdgcn_global_load_lds(
        (const __attribute__((address_space(1))) void*)(
            Vtb + (size_t)(h * 64 + srow) * SEQ + kv0 + scol8),
        (__attribute__((address_space(3))) void*)(&VsB[buf * 4096 + tid * 8]), 16, 0, 0);
  };

  f32x16 osum[2] = {};   // dm=0,1 : O^T[d = dm*32 + frag][q]
  float lsum = 0.f;

  stage(0, kvbase);
  __syncthreads();

  int cur = 0;
  for (int t = 0; t < TILES_PER_SPLIT; ++t) {
    if (t + 1 < TILES_PER_SPLIT) stage(cur ^ 1, kvbase + (t + 1) * KVB);

    const short* ks_lds = KsB + cur * 4096;
    const short* vs_lds = VsB + cur * 4096;

    // S = K x Q^T : D col = q (lane&31), regs = kv (rows kq*32 + OD(r))
    f32x16 s = {};
    __builtin_amdgcn_s_setprio(1);
#pragma unroll
    for (int kst = 0; kst < 4; ++kst) {
      int row = kq * 32 + l31;
      bf16x8 kf = *(const bf16x8*)(ks_lds + row * 64 + ((kst * 16 + hi * 8) ^ ((row & 7) * 8)));
      s = __builtin_amdgcn_mfma_f32_32x32x16_bf16(kf, qf[kst], s, 0, 0, 0);
    }
    __builtin_amdgcn_s_setprio(0);

    // p = exp2(s); pack pairs; lane-local partial row sum
    unsigned w[8];
    float ls0 = 0.f, ls1 = 0.f;
#pragma unroll
    for (int m = 0; m < 8; ++m) {
      float p0 = __builtin_amdgcn_exp2f(s[2 * m]);
      float p1 = __builtin_amdgcn_exp2f(s[2 * m + 1]);
      ls0 += p0; ls1 += p1;
      w[m] = pk2(p0, p1);
    }
    lsum += ls0 + ls1;

    // PV: O^T += V^T x P ; B-frag (n=q, k=kv16) via half-exchange
#pragma unroll
    for (int ks2 = 0; ks2 < 2; ++ks2) {
      union { unsigned u[4]; bf16x8 v; } pf;
#if __has_builtin(__builtin_amdgcn_permlane32_swap)
      {
        auto sw0 = __builtin_amdgcn_permlane32_swap(w[4 * ks2 + 0], w[4 * ks2 + 2], false, false);
        auto sw1 = __builtin_amdgcn_permlane32_swap(w[4 * ks2 + 1], w[4 * ks2 + 3], false, false);
        pf.u[0] = sw0[0]; pf.u[1] = sw1[0]; pf.u[2] = sw0[1]; pf.u[3] = sw1[1];
      }
#else
      {
        unsigned t0 = hi ? w[4 * ks2 + 0] : w[4 * ks2 + 2];
        unsigned t1 = hi ? w[4 * ks2 + 1] : w[4 * ks2 + 3];
        unsigned r0 = __shfl_xor(t0, 32);
        unsigned r1 = __shfl_xor(t1, 32);
        pf.u[0] = hi ? r0 : w[4 * ks2 + 0];
        pf.u[1] = hi ? r1 : w[4 * ks2 + 1];
        pf.u[2] = hi ? w[4 * ks2 + 2] : r0;
        pf.u[3] = hi ? w[4 * ks2 + 3] : r1;
      }
#endif
      __builtin_amdgcn_s_setprio(1);
#pragma unroll
      for (int dm = 0; dm < 2; ++dm) {
        int vrow = dm * 32 + l31;
        bf16x8 vf = *(const bf16x8*)(
            vs_lds + vrow * 64 + ((kq * 32 + ks2 * 16 + hi * 8) ^ ((vrow & 7) * 8)));
        osum[dm] = __builtin_amdgcn_mfma_f32_32x32x16_bf16(vf, pf.v, osum[dm], 0, 0, 0);
      }
      __builtin_amdgcn_s_setprio(0);
    }

    __syncthreads();   // drains glds for t+1; protects buffer reuse
    cur ^= 1;
  }

  // full per-q row sum for this wave's kq half
  lsum += __shfl_xor(lsum, 32);

  // ---- combine the 2 kq halves in LDS; write bf16 O-partial + f32 l-partial ----
  __syncthreads();                          // Ks/Vs dead
  float* bufA = (float*)arena;              // [4 rh][64 d][33 q] = 33792 B
#define OD(dm, r) ((dm) * 32 + ((r) & 3) + 8 * ((r) >> 2) + 4 * hi)
#define OADDR(dm, r) (rh * 2112 + OD(dm, r) * 33 + l31)
  if (kq == 1) {
    if (hi == 0) lzp[rh][l31] = lsum;
#pragma unroll
    for (int dm = 0; dm < 2; ++dm)
#pragma unroll
      for (int r = 0; r < 16; ++r) bufA[OADDR(dm, r)] = osum[dm][r];
  }
  __syncthreads();
  if (kq == 0) {
#pragma unroll
    for (int dm = 0; dm < 2; ++dm)
#pragma unroll
      for (int r = 0; r < 16; ++r) {
        float v = osum[dm][r] + bufA[OADDR(dm, r)];
        bufA[OADDR(dm, r)] = v;
      }
    float lt = lsum + lzp[rh][l31];
    if (hi == 0)
      lpart[(size_t)(split * NHEAD + h) * SEQ + q0 + rh * 32 + l31] = lt;
  }
  __syncthreads();
#undef OD
#undef OADDR

  // cooperative partial write: thread -> (q row, 16-d chunk)
  {
    int q_ = tid >> 2;             // 0..127
    int dc = (tid & 3) * 16;
    int qr = q_ >> 5, ql = q_ & 31;
    short ov[16];
#pragma unroll
    for (int i = 0; i < 16; ++i)
      ov[i] = f2b(bufA[qr * 2112 + (dc + i) * 33 + ql]);
    *(bf16x8*)(Opart + (size_t)(q0 + q_) * CDIM + h * 64 + dc) = *(bf16x8*)(ov);
    *(bf16x8*)(Opart + (size_t)(q0 + q_) * CDIM + h * 64 + dc + 8) = *(bf16x8*)(ov + 8);
  }
}

// ---- combine 4 kv-split partials: Ab = (sum O_s) / (sum l_s) ----
__global__ __launch_bounds__(256) void combine_kernel(
    const short* __restrict__ p0, const short* __restrict__ p1,
    const short* __restrict__ p2, const short* __restrict__ p3,
    const float* __restrict__ lpart, short* __restrict__ Ab) {
  int t = blockIdx.x * 256 + threadIdx.x;
  size_t base = (size_t)t * 8;
  int q = (int)(base >> 9), c = (int)(base & 511), h = c >> 6;
  float l = lpart[(size_t)(0 * NHEAD + h) * SEQ + q] +
            lpart[(size_t)(1 * NHEAD + h) * SEQ + q] +
            lpart[(size_t)(2 * NHEAD + h) * SEQ + q] +
            lpart[(size_t)(3 * NHEAD + h) * SEQ + q];
  float rinv = 1.f / l;
  bf16x8 a0 = *(const bf16x8*)(p0 + base);
  bf16x8 a1 = *(const bf16x8*)(p1 + base);
  bf16x8 a2 = *(const bf16x8*)(p2 + base);
  bf16x8 a3 = *(const bf16x8*)(p3 + base);
  short ov[8];
#pragma unroll
  for (int i = 0; i < 8; ++i)
    ov[i] = f2b((b2f(a0[i]) + b2f(a1[i]) + b2f(a2[i]) + b2f(a3[i])) * rinv);
  *(bf16x8*)(Ab + base) = *(bf16x8*)(ov);
}

extern "C" void kernel_launch(void* const* d_in, const int* in_sizes, int n_in,
                              void* d_out, int out_size, void* d_ws, size_t ws_size,
                              hipStream_t stream) {
  const float* x  = (const float*)d_in[0];
  const float* Wq = (const float*)d_in[1];
  const float* bq = (const float*)d_in[2];
  const float* Wk = (const float*)d_in[3];
  const float* bk = (const float*)d_in[4];
  const float* Wv = (const float*)d_in[5];
  const float* bv = (const float*)d_in[6];
  const float* Wo = (const float*)d_in[7];
  const float* bo = (const float*)d_in[8];
  float* out = (float*)d_out;

  short* ws = (short*)d_ws;
  size_t off = 0;
  short* xb  = ws + off; off += (size_t)SEQ * CDIM;   // reused as O-partial 0
  short* Wqt = ws + off; off += (size_t)CDIM * CDIM;
  short* Wkt = ws + off; off += (size_t)CDIM * CDIM;
  short* Wvt = ws + off; off += (size_t)CDIM * CDIM;
  short* Wot = ws + off; off += (size_t)CDIM * CDIM;
  short* Qb  = ws + off; off += (size_t)SEQ * CDIM;
  short* Kb  = ws + off; off += (size_t)SEQ * CDIM;
  short* Vtb = ws + off; off += (size_t)CDIM * SEQ;
  short* Ab  = ws + off; off += (size_t)SEQ * CDIM;
  short* Op1 = ws + off; off += (size_t)SEQ * CDIM;
  short* Op2 = ws + off; off += (size_t)SEQ * CDIM;
  short* Op3 = ws + off; off += (size_t)SEQ * CDIM;
  float* lpart = (float*)(ws + off); off += (size_t)NSPLIT * NHEAD * SEQ * 2;
  short* Op0 = xb;   // xb is dead after qkv_gemm

  prep_kernel<<<2048 + 4 * 256, 256, 0, stream>>>(x, Wq, Wk, Wv, Wo, xb, Wqt, Wkt, Wvt, Wot);
  qkv_gemm_kernel<<<dim3(SEQ / 64, CDIM / 64, 3), 256, 0, stream>>>(
      xb, Wqt, Wkt, Wvt, bq, bk, bv, Qb, Kb, Vtb);
  attn_kernel<<<(SEQ / 128) * NHEAD * NSPLIT, 512, 0, stream>>>(
      Qb, Kb, Vtb, Op0, Op1, Op2, Op3, lpart);
  combine_kernel<<<SEQ * CDIM / 8 / 256, 256, 0, stream>>>(Op0, Op1, Op2, Op3, lpart, Ab);
  out_gemm_kernel<<<dim3(SEQ / 64, CDIM / 64), 256, 0, stream>>>(Ab, Wot, bo, out);
}

// Round 7
// 88.721 us; speedup vs baseline: 1.9856x; 1.9856x over previous
//
#include <hip/hip_runtime.h>
#include <hip/hip_bf16.h>

#define SEQ 4096
#define CDIM 512
#define NHEAD 8
#define HDIM 64
#define KVB 64
#define NSPLIT 4
#define TILES_PER_SPLIT (SEQ / KVB / NSPLIT)   // 16

typedef __attribute__((ext_vector_type(8))) short bf16x8;
typedef __attribute__((ext_vector_type(4))) float f32x4;
typedef __attribute__((ext_vector_type(16))) float f32x16;

__device__ __forceinline__ short f2b(float f) {
  union { float f; unsigned u; } v; v.f = f;
  unsigned u = v.u;
  unsigned r = u + 0x7fffu + ((u >> 16) & 1u);
  return (short)(r >> 16);
}
__device__ __forceinline__ float b2f(short s) {
  union { unsigned u; float f; } v; v.u = ((unsigned)(unsigned short)s) << 16;
  return v.f;
}
__device__ __forceinline__ unsigned pk2(float a, float b) {
  union { __hip_bfloat162 h; unsigned u; } z;
  z.h = __float22bfloat162_rn(make_float2(a, b));
  return z.u;
}

// ---- prep: fp32->bf16 convert of x (blocks 0..2047) + 4 weight transposes ----
__global__ __launch_bounds__(256) void prep_kernel(
    const float* __restrict__ x,
    const float* __restrict__ Wq, const float* __restrict__ Wk,
    const float* __restrict__ Wv, const float* __restrict__ Wo,
    short* __restrict__ xb,
    short* __restrict__ Wqt, short* __restrict__ Wkt,
    short* __restrict__ Wvt, short* __restrict__ Wot) {
  __shared__ short tile[32][33];
  int b = blockIdx.x, tid = threadIdx.x;
  if (b < 2048) {
    int i = (b * 256 + tid) * 4;
    float4 v = *(const float4*)(x + i);
    short4 o;
    o.x = f2b(v.x); o.y = f2b(v.y); o.z = f2b(v.z); o.w = f2b(v.w);
    *(short4*)(xb + i) = o;
    return;
  }
  int t = b - 2048;
  int mat = t >> 8; t &= 255;
  const float* W = mat == 0 ? Wq : mat == 1 ? Wk : mat == 2 ? Wv : Wo;
  short* Wt = mat == 0 ? Wqt : mat == 1 ? Wkt : mat == 2 ? Wvt : Wot;
  int n0 = (t & 15) * 32, k0 = (t >> 4) * 32;
  int tx = tid & 31, ty = tid >> 5;  // 32 x 8
  for (int i = 0; i < 32; i += 8)
    tile[ty + i][tx] = f2b(W[(size_t)(k0 + ty + i) * CDIM + n0 + tx]);
  __syncthreads();
  for (int i = 0; i < 32; i += 8)
    Wt[(size_t)(n0 + ty + i) * CDIM + k0 + tx] = tile[tx][ty + i];
}

// ---- fused QKV GEMM: z=0 -> Q (bf16 [M][N]), z=1 -> K, z=2 -> V transposed [N][M] ----
__global__ __launch_bounds__(256) void qkv_gemm_kernel(
    const short* __restrict__ A,
    const short* __restrict__ Wqt, const short* __restrict__ Wkt, const short* __restrict__ Wvt,
    const float* __restrict__ bq, const float* __restrict__ bk, const float* __restrict__ bv,
    short* __restrict__ Qb, short* __restrict__ Kb, short* __restrict__ Vtb) {
  __shared__ short As[64 * 64];
  __shared__ short Bs[64 * 64];
  const int z = blockIdx.z;
  const short* Bt = z == 0 ? Wqt : z == 1 ? Wkt : Wvt;
  const float* bias = z == 0 ? bq : z == 1 ? bk : bv;
  const int m0 = blockIdx.x * 64, n0 = blockIdx.y * 64;
  const int tid = threadIdx.x;
  const int w = tid >> 6, lane = tid & 63, g = lane >> 4, l16 = lane & 15;
  f32x4 acc[4] = {};
  for (int kt = 0; kt < CDIM; kt += 64) {
    __syncthreads();
    for (int it = 0; it < 2; ++it) {
      int c = tid + it * 256;
      int r = c >> 3, cc = (c & 7) * 8;
      int sw = r * 64 + (cc ^ ((r & 7) * 8));
      *(bf16x8*)(As + sw) = *(const bf16x8*)(A + (size_t)(m0 + r) * CDIM + kt + cc);
      *(bf16x8*)(Bs + sw) = *(const bf16x8*)(Bt + (size_t)(n0 + r) * CDIM + kt + cc);
    }
    __syncthreads();
    const int ar = w * 16 + l16;
    for (int ks = 0; ks < 2; ++ks) {
      int c0 = ks * 32 + 8 * g;
      bf16x8 af = *(const bf16x8*)(As + ar * 64 + (c0 ^ ((ar & 7) * 8)));
      for (int ni = 0; ni < 4; ++ni) {
        int br = ni * 16 + l16;
        bf16x8 bf = *(const bf16x8*)(Bs + br * 64 + (c0 ^ ((br & 7) * 8)));
        acc[ni] = __builtin_amdgcn_mfma_f32_16x16x32_bf16(af, bf, acc[ni], 0, 0, 0);
      }
    }
  }
  for (int ni = 0; ni < 4; ++ni) {
    int col = n0 + ni * 16 + l16;
    float bv_ = bias[col];
    for (int j = 0; j < 4; ++j) {
      int row = m0 + w * 16 + g * 4 + j;
      float v = acc[ni][j] + bv_;
      if (z == 0)      Qb[(size_t)row * CDIM + col] = f2b(v);
      else if (z == 1) Kb[(size_t)row * CDIM + col] = f2b(v);
      else             Vtb[(size_t)col * SEQ + row] = f2b(v);
    }
  }
}

// ---- output projection GEMM: fp32 out ----
__global__ __launch_bounds__(256) void out_gemm_kernel(
    const short* __restrict__ A, const short* __restrict__ Bt,
    const float* __restrict__ bias, float* __restrict__ out) {
  __shared__ short As[64 * 64];
  __shared__ short Bs[64 * 64];
  const int m0 = blockIdx.x * 64, n0 = blockIdx.y * 64;
  const int tid = threadIdx.x;
  const int w = tid >> 6, lane = tid & 63, g = lane >> 4, l16 = lane & 15;
  f32x4 acc[4] = {};
  for (int kt = 0; kt < CDIM; kt += 64) {
    __syncthreads();
    for (int it = 0; it < 2; ++it) {
      int c = tid + it * 256;
      int r = c >> 3, cc = (c & 7) * 8;
      int sw = r * 64 + (cc ^ ((r & 7) * 8));
      *(bf16x8*)(As + sw) = *(const bf16x8*)(A + (size_t)(m0 + r) * CDIM + kt + cc);
      *(bf16x8*)(Bs + sw) = *(const bf16x8*)(Bt + (size_t)(n0 + r) * CDIM + kt + cc);
    }
    __syncthreads();
    const int ar = w * 16 + l16;
    for (int ks = 0; ks < 2; ++ks) {
      int c0 = ks * 32 + 8 * g;
      bf16x8 af = *(const bf16x8*)(As + ar * 64 + (c0 ^ ((ar & 7) * 8)));
      for (int ni = 0; ni < 4; ++ni) {
        int br = ni * 16 + l16;
        bf16x8 bf = *(const bf16x8*)(Bs + br * 64 + (c0 ^ ((br & 7) * 8)));
        acc[ni] = __builtin_amdgcn_mfma_f32_16x16x32_bf16(af, bf, acc[ni], 0, 0, 0);
      }
    }
  }
  for (int ni = 0; ni < 4; ++ni) {
    int col = n0 + ni * 16 + l16;
    float bv_ = bias[col];
    for (int j = 0; j < 4; ++j) {
      int row = m0 + w * 16 + g * 4 + j;
      out[(size_t)row * CDIM + col] = acc[ni][j] + bv_;
    }
  }
}

// ---- flash attention partials. Grid: 32 qtiles x 8 heads x 4 kv-splits = 1024
// blocks, 512 threads = 8 waves = 4 rh (32 q each, q-tile 128) x 2 kq (32 kv).
// KVB=64, K/V double-buffered via global_load_lds; 1 barrier/iter.
// launch_bounds(512,4): R6's (512,8) forced a 64-reg budget -> spills ->
// 400MB scratch traffic. 128-reg cap keeps VGPR ~52-60 (<=64), so 4 blocks/CU
// remain possible via LDS (34KB) without strangling the allocator.
__global__ __launch_bounds__(512, 4) void attn_kernel(
    const short* __restrict__ Qb,   // [SEQ][CDIM] bf16
    const short* __restrict__ Kb,   // [SEQ][CDIM] bf16
    const short* __restrict__ Vtb,  // [CDIM][SEQ] bf16 (d-major)
    short* __restrict__ Op0, short* __restrict__ Op1,
    short* __restrict__ Op2, short* __restrict__ Op3,
    float* __restrict__ lpart) {    // [NSPLIT][NHEAD][SEQ]
  __shared__ __align__(16) char arena[33792];   // Ks[2][4096] + Vs[2][4096]; epi: bufA[4*64*33] f32
  __shared__ float lzp[4][32];
  short* KsB = (short*)arena;
  short* VsB = (short*)(arena + 16384);
  const int bid = blockIdx.x;
  const int h = bid & 7;                 // head ~ XCD
  const int rest = bid >> 3;
  const int split = rest & 3;
  const int q0 = (rest >> 2) * 128;
  const int kvbase = split * (TILES_PER_SPLIT * KVB);
  const int tid = threadIdx.x;
  const int wid = tid >> 6, lane = tid & 63;
  const int l31 = lane & 31, hi = lane >> 5;
  const int rh = wid >> 1, kq = wid & 1;
  const float scale2 = 0.06375872274f;   // (1/sqrt(512)) * log2(e)

  short* Opart = split == 0 ? Op0 : split == 1 ? Op1 : split == 2 ? Op2 : Op3;

  // Q in B-frag layout (n=q=lane&31, k-slices of d), pre-scaled
  bf16x8 qf[4];
  {
    int qrow = q0 + rh * 32 + l31;
#pragma unroll
    for (int kst = 0; kst < 4; ++kst) {
      bf16x8 q = *(const bf16x8*)(Qb + (size_t)qrow * CDIM + h * 64 + kst * 16 + hi * 8);
#pragma unroll
      for (int i = 0; i < 8; ++i) q[i] = f2b(b2f(q[i]) * scale2);
      qf[kst] = q;
    }
  }

  // glds staging: linear LDS dest (tid*16B), inverse-swizzled global source col
  const int srow = tid >> 3;                       // 0..63 (K: kv row; V: d row)
  const int scol8 = 8 * ((tid & 7) ^ (srow & 7));
  auto stage = [&](int buf, int kv0) {
    __builtin_amdgcn_global_load_lds(
        (const __attribute__((address_space(1))) void*)(
            Kb + (size_t)(kv0 + srow) * CDIM + h * 64 + scol8),
        (__attribute__((address_space(3))) void*)(&KsB[buf * 4096 + tid * 8]), 16, 0, 0);
    __builtin_amdgcn_global_load_lds(
        (const __attribute__((address_space(1))) void*)(
            Vtb + (size_t)(h * 64 + srow) * SEQ + kv0 + scol8),
        (__attribute__((address_space(3))) void*)(&VsB[buf * 4096 + tid * 8]), 16, 0, 0);
  };

  f32x16 osum[2] = {};   // dm=0,1 : O^T[d = dm*32 + frag][q]
  float lsum = 0.f;

  stage(0, kvbase);
  __syncthreads();

  int cur = 0;
  for (int t = 0; t < TILES_PER_SPLIT; ++t) {
    if (t + 1 < TILES_PER_SPLIT) stage(cur ^ 1, kvbase + (t + 1) * KVB);

    const short* ks_lds = KsB + cur * 4096;
    const short* vs_lds = VsB + cur * 4096;

    // S = K x Q^T : D col = q (lane&31), regs = kv (rows kq*32 + OD(r))
    f32x16 s = {};
    __builtin_amdgcn_s_setprio(1);
#pragma unroll
    for (int kst = 0; kst < 4; ++kst) {
      int row = kq * 32 + l31;
      bf16x8 kf = *(const bf16x8*)(ks_lds + row * 64 + ((kst * 16 + hi * 8) ^ ((row & 7) * 8)));
      s = __builtin_amdgcn_mfma_f32_32x32x16_bf16(kf, qf[kst], s, 0, 0, 0);
    }
    __builtin_amdgcn_s_setprio(0);

    // p = exp2(s); pack pairs; lane-local partial row sum
    unsigned w[8];
    float ls0 = 0.f, ls1 = 0.f;
#pragma unroll
    for (int m = 0; m < 8; ++m) {
      float p0 = __builtin_amdgcn_exp2f(s[2 * m]);
      float p1 = __builtin_amdgcn_exp2f(s[2 * m + 1]);
      ls0 += p0; ls1 += p1;
      w[m] = pk2(p0, p1);
    }
    lsum += ls0 + ls1;

    // PV: O^T += V^T x P ; B-frag (n=q, k=kv16) via half-exchange
#pragma unroll
    for (int ks2 = 0; ks2 < 2; ++ks2) {
      union { unsigned u[4]; bf16x8 v; } pf;
#if __has_builtin(__builtin_amdgcn_permlane32_swap)
      {
        auto sw0 = __builtin_amdgcn_permlane32_swap(w[4 * ks2 + 0], w[4 * ks2 + 2], false, false);
        auto sw1 = __builtin_amdgcn_permlane32_swap(w[4 * ks2 + 1], w[4 * ks2 + 3], false, false);
        pf.u[0] = sw0[0]; pf.u[1] = sw1[0]; pf.u[2] = sw0[1]; pf.u[3] = sw1[1];
      }
#else
      {
        unsigned t0 = hi ? w[4 * ks2 + 0] : w[4 * ks2 + 2];
        unsigned t1 = hi ? w[4 * ks2 + 1] : w[4 * ks2 + 3];
        unsigned r0 = __shfl_xor(t0, 32);
        unsigned r1 = __shfl_xor(t1, 32);
        pf.u[0] = hi ? r0 : w[4 * ks2 + 0];
        pf.u[1] = hi ? r1 : w[4 * ks2 + 1];
        pf.u[2] = hi ? w[4 * ks2 + 2] : r0;
        pf.u[3] = hi ? w[4 * ks2 + 3] : r1;
      }
#endif
      __builtin_amdgcn_s_setprio(1);
#pragma unroll
      for (int dm = 0; dm < 2; ++dm) {
        int vrow = dm * 32 + l31;
        bf16x8 vf = *(const bf16x8*)(
            vs_lds + vrow * 64 + ((kq * 32 + ks2 * 16 + hi * 8) ^ ((vrow & 7) * 8)));
        osum[dm] = __builtin_amdgcn_mfma_f32_32x32x16_bf16(vf, pf.v, osum[dm], 0, 0, 0);
      }
      __builtin_amdgcn_s_setprio(0);
    }

    __syncthreads();   // drains glds for t+1; protects buffer reuse
    cur ^= 1;
  }

  // full per-q row sum for this wave's kq half
  lsum += __shfl_xor(lsum, 32);

  // ---- combine the 2 kq halves in LDS; write bf16 O-partial + f32 l-partial ----
  __syncthreads();                          // Ks/Vs dead
  float* bufA = (float*)arena;              // [4 rh][64 d][33 q] = 33792 B
#define OD(dm, r) ((dm) * 32 + ((r) & 3) + 8 * ((r) >> 2) + 4 * hi)
#define OADDR(dm, r) (rh * 2112 + OD(dm, r) * 33 + l31)
  if (kq == 1) {
    if (hi == 0) lzp[rh][l31] = lsum;
#pragma unroll
    for (int dm = 0; dm < 2; ++dm)
#pragma unroll
      for (int r = 0; r < 16; ++r) bufA[OADDR(dm, r)] = osum[dm][r];
  }
  __syncthreads();
  if (kq == 0) {
#pragma unroll
    for (int dm = 0; dm < 2; ++dm)
#pragma unroll
      for (int r = 0; r < 16; ++r) {
        float v = osum[dm][r] + bufA[OADDR(dm, r)];
        bufA[OADDR(dm, r)] = v;
      }
    float lt = lsum + lzp[rh][l31];
    if (hi == 0)
      lpart[(size_t)(split * NHEAD + h) * SEQ + q0 + rh * 32 + l31] = lt;
  }
  __syncthreads();
#undef OD
#undef OADDR

  // cooperative partial write: thread -> (q row, 16-d chunk)
  {
    int q_ = tid >> 2;             // 0..127
    int dc = (tid & 3) * 16;
    int qr = q_ >> 5, ql = q_ & 31;
    short ov[16];
#pragma unroll
    for (int i = 0; i < 16; ++i)
      ov[i] = f2b(bufA[qr * 2112 + (dc + i) * 33 + ql]);
    *(bf16x8*)(Opart + (size_t)(q0 + q_) * CDIM + h * 64 + dc) = *(bf16x8*)(ov);
    *(bf16x8*)(Opart + (size_t)(q0 + q_) * CDIM + h * 64 + dc + 8) = *(bf16x8*)(ov + 8);
  }
}

// ---- combine 4 kv-split partials: Ab = (sum O_s) / (sum l_s) ----
__global__ __launch_bounds__(256) void combine_kernel(
    const short* __restrict__ p0, const short* __restrict__ p1,
    const short* __restrict__ p2, const short* __restrict__ p3,
    const float* __restrict__ lpart, short* __restrict__ Ab) {
  int t = blockIdx.x * 256 + threadIdx.x;
  size_t base = (size_t)t * 8;
  int q = (int)(base >> 9), c = (int)(base & 511), h = c >> 6;
  float l = lpart[(size_t)(0 * NHEAD + h) * SEQ + q] +
            lpart[(size_t)(1 * NHEAD + h) * SEQ + q] +
            lpart[(size_t)(2 * NHEAD + h) * SEQ + q] +
            lpart[(size_t)(3 * NHEAD + h) * SEQ + q];
  float rinv = 1.f / l;
  bf16x8 a0 = *(const bf16x8*)(p0 + base);
  bf16x8 a1 = *(const bf16x8*)(p1 + base);
  bf16x8 a2 = *(const bf16x8*)(p2 + base);
  bf16x8 a3 = *(const bf16x8*)(p3 + base);
  short ov[8];
#pragma unroll
  for (int i = 0; i < 8; ++i)
    ov[i] = f2b((b2f(a0[i]) + b2f(a1[i]) + b2f(a2[i]) + b2f(a3[i])) * rinv);
  *(bf16x8*)(Ab + base) = *(bf16x8*)(ov);
}

extern "C" void kernel_launch(void* const* d_in, const int* in_sizes, int n_in,
                              void* d_out, int out_size, void* d_ws, size_t ws_size,
                              hipStream_t stream) {
  const float* x  = (const float*)d_in[0];
  const float* Wq = (const float*)d_in[1];
  const float* bq = (const float*)d_in[2];
  const float* Wk = (const float*)d_in[3];
  const float* bk = (const float*)d_in[4];
  const float* Wv = (const float*)d_in[5];
  const float* bv = (const float*)d_in[6];
  const float* Wo = (const float*)d_in[7];
  const float* bo = (const float*)d_in[8];
  float* out = (float*)d_out;

  short* ws = (short*)d_ws;
  size_t off = 0;
  short* xb  = ws + off; off += (size_t)SEQ * CDIM;   // reused as O-partial 0
  short* Wqt = ws + off; off += (size_t)CDIM * CDIM;
  short* Wkt = ws + off; off += (size_t)CDIM * CDIM;
  short* Wvt = ws + off; off += (size_t)CDIM * CDIM;
  short* Wot = ws + off; off += (size_t)CDIM * CDIM;
  short* Qb  = ws + off; off += (size_t)SEQ * CDIM;
  short* Kb  = ws + off; off += (size_t)SEQ * CDIM;
  short* Vtb = ws + off; off += (size_t)CDIM * SEQ;
  short* Ab  = ws + off; off += (size_t)SEQ * CDIM;
  short* Op1 = ws + off; off += (size_t)SEQ * CDIM;
  short* Op2 = ws + off; off += (size_t)SEQ * CDIM;
  short* Op3 = ws + off; off += (size_t)SEQ * CDIM;
  float* lpart = (float*)(ws + off); off += (size_t)NSPLIT * NHEAD * SEQ * 2;
  short* Op0 = xb;   // xb is dead after qkv_gemm

  prep_kernel<<<2048 + 4 * 256, 256, 0, stream>>>(x, Wq, Wk, Wv, Wo, xb, Wqt, Wkt, Wvt, Wot);
  qkv_gemm_kernel<<<dim3(SEQ / 64, CDIM / 64, 3), 256, 0, stream>>>(
      xb, Wqt, Wkt, Wvt, bq, bk, bv, Qb, Kb, Vtb);
  attn_kernel<<<(SEQ / 128) * NHEAD * NSPLIT, 512, 0, stream>>>(
      Qb, Kb, Vtb, Op0, Op1, Op2, Op3, lpart);
  combine_kernel<<<SEQ * CDIM / 8 / 256, 256, 0, stream>>>(Op0, Op1, Op2, Op3, lpart, Ab);
  out_gemm_kernel<<<dim3(SEQ / 64, CDIM / 64), 256, 0, stream>>>(Ab, Wot, bo, out);
}

// Round 8
// 87.458 us; speedup vs baseline: 2.0143x; 1.0144x over previous
//
#include <hip/hip_runtime.h>
#include <hip/hip_bf16.h>

#define SEQ 4096
#define CDIM 512
#define NHEAD 8
#define HDIM 64
#define KVB 64
#define NSPLIT 4
#define TILES_PER_SPLIT (SEQ / KVB / NSPLIT)   // 16

typedef __attribute__((ext_vector_type(8))) short bf16x8;
typedef __attribute__((ext_vector_type(4))) float f32x4;
typedef __attribute__((ext_vector_type(16))) float f32x16;

__device__ __forceinline__ short f2b(float f) {
  union { float f; unsigned u; } v; v.f = f;
  unsigned u = v.u;
  unsigned r = u + 0x7fffu + ((u >> 16) & 1u);
  return (short)(r >> 16);
}
__device__ __forceinline__ float b2f(short s) {
  union { unsigned u; float f; } v; v.u = ((unsigned)(unsigned short)s) << 16;
  return v.f;
}
__device__ __forceinline__ unsigned pk2(float a, float b) {
  union { __hip_bfloat162 h; unsigned u; } z;
  z.h = __float22bfloat162_rn(make_float2(a, b));
  return z.u;
}

// ---- prep: fp32->bf16 convert of x (blocks 0..2047) + 4 weight transposes ----
__global__ __launch_bounds__(256) void prep_kernel(
    const float* __restrict__ x,
    const float* __restrict__ Wq, const float* __restrict__ Wk,
    const float* __restrict__ Wv, const float* __restrict__ Wo,
    short* __restrict__ xb,
    short* __restrict__ Wqt, short* __restrict__ Wkt,
    short* __restrict__ Wvt, short* __restrict__ Wot) {
  __shared__ short tile[32][33];
  int b = blockIdx.x, tid = threadIdx.x;
  if (b < 2048) {
    int i = (b * 256 + tid) * 4;
    float4 v = *(const float4*)(x + i);
    short4 o;
    o.x = f2b(v.x); o.y = f2b(v.y); o.z = f2b(v.z); o.w = f2b(v.w);
    *(short4*)(xb + i) = o;
    return;
  }
  int t = b - 2048;
  int mat = t >> 8; t &= 255;
  const float* W = mat == 0 ? Wq : mat == 1 ? Wk : mat == 2 ? Wv : Wo;
  short* Wt = mat == 0 ? Wqt : mat == 1 ? Wkt : mat == 2 ? Wvt : Wot;
  int n0 = (t & 15) * 32, k0 = (t >> 4) * 32;
  int tx = tid & 31, ty = tid >> 5;  // 32 x 8
  for (int i = 0; i < 32; i += 8)
    tile[ty + i][tx] = f2b(W[(size_t)(k0 + ty + i) * CDIM + n0 + tx]);
  __syncthreads();
  for (int i = 0; i < 32; i += 8)
    Wt[(size_t)(n0 + ty + i) * CDIM + k0 + tx] = tile[tx][ty + i];
}

// ---- fused QKV GEMM: z=0 -> Q (bf16 [M][N]), z=1 -> K, z=2 -> V transposed [N][M] ----
__global__ __launch_bounds__(256) void qkv_gemm_kernel(
    const short* __restrict__ A,
    const short* __restrict__ Wqt, const short* __restrict__ Wkt, const short* __restrict__ Wvt,
    const float* __restrict__ bq, const float* __restrict__ bk, const float* __restrict__ bv,
    short* __restrict__ Qb, short* __restrict__ Kb, short* __restrict__ Vtb) {
  __shared__ short As[64 * 64];
  __shared__ short Bs[64 * 64];
  const int z = blockIdx.z;
  const short* Bt = z == 0 ? Wqt : z == 1 ? Wkt : Wvt;
  const float* bias = z == 0 ? bq : z == 1 ? bk : bv;
  const int m0 = blockIdx.x * 64, n0 = blockIdx.y * 64;
  const int tid = threadIdx.x;
  const int w = tid >> 6, lane = tid & 63, g = lane >> 4, l16 = lane & 15;
  f32x4 acc[4] = {};
  for (int kt = 0; kt < CDIM; kt += 64) {
    __syncthreads();
    for (int it = 0; it < 2; ++it) {
      int c = tid + it * 256;
      int r = c >> 3, cc = (c & 7) * 8;
      int sw = r * 64 + (cc ^ ((r & 7) * 8));
      *(bf16x8*)(As + sw) = *(const bf16x8*)(A + (size_t)(m0 + r) * CDIM + kt + cc);
      *(bf16x8*)(Bs + sw) = *(const bf16x8*)(Bt + (size_t)(n0 + r) * CDIM + kt + cc);
    }
    __syncthreads();
    const int ar = w * 16 + l16;
    for (int ks = 0; ks < 2; ++ks) {
      int c0 = ks * 32 + 8 * g;
      bf16x8 af = *(const bf16x8*)(As + ar * 64 + (c0 ^ ((ar & 7) * 8)));
      for (int ni = 0; ni < 4; ++ni) {
        int br = ni * 16 + l16;
        bf16x8 bf = *(const bf16x8*)(Bs + br * 64 + (c0 ^ ((br & 7) * 8)));
        acc[ni] = __builtin_amdgcn_mfma_f32_16x16x32_bf16(af, bf, acc[ni], 0, 0, 0);
      }
    }
  }
  for (int ni = 0; ni < 4; ++ni) {
    int col = n0 + ni * 16 + l16;
    float bv_ = bias[col];
    for (int j = 0; j < 4; ++j) {
      int row = m0 + w * 16 + g * 4 + j;
      float v = acc[ni][j] + bv_;
      if (z == 0)      Qb[(size_t)row * CDIM + col] = f2b(v);
      else if (z == 1) Kb[(size_t)row * CDIM + col] = f2b(v);
      else             Vtb[(size_t)col * SEQ + row] = f2b(v);
    }
  }
}

// ---- output projection GEMM: fp32 out ----
__global__ __launch_bounds__(256) void out_gemm_kernel(
    const short* __restrict__ A, const short* __restrict__ Bt,
    const float* __restrict__ bias, float* __restrict__ out) {
  __shared__ short As[64 * 64];
  __shared__ short Bs[64 * 64];
  const int m0 = blockIdx.x * 64, n0 = blockIdx.y * 64;
  const int tid = threadIdx.x;
  const int w = tid >> 6, lane = tid & 63, g = lane >> 4, l16 = lane & 15;
  f32x4 acc[4] = {};
  for (int kt = 0; kt < CDIM; kt += 64) {
    __syncthreads();
    for (int it = 0; it < 2; ++it) {
      int c = tid + it * 256;
      int r = c >> 3, cc = (c & 7) * 8;
      int sw = r * 64 + (cc ^ ((r & 7) * 8));
      *(bf16x8*)(As + sw) = *(const bf16x8*)(A + (size_t)(m0 + r) * CDIM + kt + cc);
      *(bf16x8*)(Bs + sw) = *(const bf16x8*)(Bt + (size_t)(n0 + r) * CDIM + kt + cc);
    }
    __syncthreads();
    const int ar = w * 16 + l16;
    for (int ks = 0; ks < 2; ++ks) {
      int c0 = ks * 32 + 8 * g;
      bf16x8 af = *(const bf16x8*)(As + ar * 64 + (c0 ^ ((ar & 7) * 8)));
      for (int ni = 0; ni < 4; ++ni) {
        int br = ni * 16 + l16;
        bf16x8 bf = *(const bf16x8*)(Bs + br * 64 + (c0 ^ ((br & 7) * 8)));
        acc[ni] = __builtin_amdgcn_mfma_f32_16x16x32_bf16(af, bf, acc[ni], 0, 0, 0);
      }
    }
  }
  for (int ni = 0; ni < 4; ++ni) {
    int col = n0 + ni * 16 + l16;
    float bv_ = bias[col];
    for (int j = 0; j < 4; ++j) {
      int row = m0 + w * 16 + g * 4 + j;
      out[(size_t)row * CDIM + col] = acc[ni][j] + bv_;
    }
  }
}

// ---- flash attention partials, 1-tile-ahead software pipeline.
// Grid: 32 qtiles x 8 heads x 4 kv-splits = 1024 blocks, 512 threads =
// 8 waves = 4 rh (32 q) x 2 kq (32 kv). KVB=64, TRIPLE-buffered LDS.
// Phase t: stage(t+2) || PV(t) from carried w[8] || QK(t+1) -> new w.
// Unrolled x3 so all LDS addresses are compile-time constants.
__global__ __launch_bounds__(512, 4) void attn_kernel(
    const short* __restrict__ Qb,   // [SEQ][CDIM] bf16
    const short* __restrict__ Kb,   // [SEQ][CDIM] bf16
    const short* __restrict__ Vtb,  // [CDIM][SEQ] bf16 (d-major)
    short* __restrict__ Op0, short* __restrict__ Op1,
    short* __restrict__ Op2, short* __restrict__ Op3,
    float* __restrict__ lpart) {    // [NSPLIT][NHEAD][SEQ]
  __shared__ __align__(16) char arena[49152];   // K 3x8KB + V 3x8KB; epi: bufA[4][64][33] f32
  __shared__ float lzp[4][32];
  short* KsB = (short*)arena;                   // KsB + b*4096
  short* VsB = (short*)(arena + 24576);         // VsB + b*4096
  const int bid = blockIdx.x;
  const int h = bid & 7;                 // head ~ XCD
  const int rest = bid >> 3;
  const int split = rest & 3;
  const int q0 = (rest >> 2) * 128;
  const int kvbase = split * (TILES_PER_SPLIT * KVB);
  const int tid = threadIdx.x;
  const int wid = tid >> 6, lane = tid & 63;
  const int l31 = lane & 31, hi = lane >> 5;
  const int rh = wid >> 1, kq = wid & 1;
  const float scale2 = 0.06375872274f;   // (1/sqrt(512)) * log2(e)

  short* Opart = split == 0 ? Op0 : split == 1 ? Op1 : split == 2 ? Op2 : Op3;

  // Q in B-frag layout (n=q=lane&31, k-slices of d), pre-scaled
  bf16x8 qf[4];
  {
    int qrow = q0 + rh * 32 + l31;
#pragma unroll
    for (int kst = 0; kst < 4; ++kst) {
      bf16x8 q = *(const bf16x8*)(Qb + (size_t)qrow * CDIM + h * 64 + kst * 16 + hi * 8);
#pragma unroll
      for (int i = 0; i < 8; ++i) q[i] = f2b(b2f(q[i]) * scale2);
      qf[kst] = q;
    }
  }

  // glds staging pointers, strength-reduced: advance by constant per stage
  const int srow = tid >> 3;                       // 0..63 (K: kv row; V: d row)
  const int scol8 = 8 * ((tid & 7) ^ (srow & 7));  // inverse-swizzled source col
  const short* kstage = Kb + (size_t)(kvbase + srow) * CDIM + h * 64 + scol8;
  const short* vstage = Vtb + (size_t)(h * 64 + srow) * SEQ + kvbase + scol8;
  auto stage = [&](short* sK, short* sV) {
    __builtin_amdgcn_global_load_lds(
        (const __attribute__((address_space(1))) void*)kstage,
        (__attribute__((address_space(3))) void*)(sK + tid * 8), 16, 0, 0);
    __builtin_amdgcn_global_load_lds(
        (const __attribute__((address_space(1))) void*)vstage,
        (__attribute__((address_space(3))) void*)(sV + tid * 8), 16, 0, 0);
    kstage += KVB * CDIM;
    vstage += KVB;
  };

  f32x16 osum[2] = {};   // dm=0,1 : O^T[d = dm*32 + frag][q]
  float lsum = 0.f;
  unsigned w[8];         // carried P (bf16x2 pairs) for the PV of the previous tile

  // softmax: s -> w + lsum
  auto softmax = [&](f32x16& s) {
    float ls0 = 0.f, ls1 = 0.f;
#pragma unroll
    for (int m = 0; m < 8; ++m) {
      float p0 = __builtin_amdgcn_exp2f(s[2 * m]);
      float p1 = __builtin_amdgcn_exp2f(s[2 * m + 1]);
      ls0 += p0; ls1 += p1;
      w[m] = pk2(p0, p1);
    }
    lsum += ls0 + ls1;
  };

  // one pipeline phase: PV(prev tile, vbuf) + QK(next tile, kbuf) + stage
  auto phase = [&](const short* vbuf, const short* kbuf, short* sK, short* sV, bool do_st) {
    if (do_st) stage(sK, sV);
    // build PV B-frags from carried w (tile t)
    union { unsigned u[4]; bf16x8 v; } pf0, pf1;
#if __has_builtin(__builtin_amdgcn_permlane32_swap)
    {
      auto a0 = __builtin_amdgcn_permlane32_swap(w[0], w[2], false, false);
      auto a1 = __builtin_amdgcn_permlane32_swap(w[1], w[3], false, false);
      auto a2 = __builtin_amdgcn_permlane32_swap(w[4], w[6], false, false);
      auto a3 = __builtin_amdgcn_permlane32_swap(w[5], w[7], false, false);
      pf0.u[0] = a0[0]; pf0.u[1] = a1[0]; pf0.u[2] = a0[1]; pf0.u[3] = a1[1];
      pf1.u[0] = a2[0]; pf1.u[1] = a3[0]; pf1.u[2] = a2[1]; pf1.u[3] = a3[1];
    }
#else
    {
      unsigned t0 = hi ? w[0] : w[2], t1 = hi ? w[1] : w[3];
      unsigned t2 = hi ? w[4] : w[6], t3 = hi ? w[5] : w[7];
      unsigned r0 = __shfl_xor(t0, 32), r1 = __shfl_xor(t1, 32);
      unsigned r2 = __shfl_xor(t2, 32), r3 = __shfl_xor(t3, 32);
      pf0.u[0] = hi ? r0 : w[0]; pf0.u[1] = hi ? r1 : w[1];
      pf0.u[2] = hi ? w[2] : r0; pf0.u[3] = hi ? w[3] : r1;
      pf1.u[0] = hi ? r2 : w[4]; pf1.u[1] = hi ? r3 : w[5];
      pf1.u[2] = hi ? w[6] : r2; pf1.u[3] = hi ? w[7] : r3;
    }
#endif
    // QK (tile t+1) and PV (tile t) MFMA clusters — independent, interleavable
    f32x16 s = {};
    __builtin_amdgcn_s_setprio(1);
#pragma unroll
    for (int kst = 0; kst < 4; ++kst) {
      int row = kq * 32 + l31;
      bf16x8 kf = *(const bf16x8*)(kbuf + row * 64 + ((kst * 16 + hi * 8) ^ ((row & 7) * 8)));
      s = __builtin_amdgcn_mfma_f32_32x32x16_bf16(kf, qf[kst], s, 0, 0, 0);
    }
#pragma unroll
    for (int dm = 0; dm < 2; ++dm) {
      int vrow = dm * 32 + l31;
      bf16x8 vf0 = *(const bf16x8*)(vbuf + vrow * 64 + ((kq * 32 + hi * 8) ^ ((vrow & 7) * 8)));
      osum[dm] = __builtin_amdgcn_mfma_f32_32x32x16_bf16(vf0, pf0.v, osum[dm], 0, 0, 0);
      bf16x8 vf1 = *(const bf16x8*)(vbuf + vrow * 64 + ((kq * 32 + 16 + hi * 8) ^ ((vrow & 7) * 8)));
      osum[dm] = __builtin_amdgcn_mfma_f32_32x32x16_bf16(vf1, pf1.v, osum[dm], 0, 0, 0);
    }
    __builtin_amdgcn_s_setprio(0);
    softmax(s);          // overwrites w with tile t+1's P
    __syncthreads();     // drains stage(t+2); next phase may read it
  };

  // prologue: tiles 0 and 1
  stage(KsB, VsB);
  __syncthreads();
  stage(KsB + 4096, VsB + 4096);
  {
    f32x16 s = {};
#pragma unroll
    for (int kst = 0; kst < 4; ++kst) {
      int row = kq * 32 + l31;
      bf16x8 kf = *(const bf16x8*)(KsB + row * 64 + ((kst * 16 + hi * 8) ^ ((row & 7) * 8)));
      s = __builtin_amdgcn_mfma_f32_32x32x16_bf16(kf, qf[kst], s, 0, 0, 0);
    }
    softmax(s);          // w = tile0's P
  }
  __syncthreads();       // tile1 ready

  // steady state: 15 phases (t = 0..14), unrolled x3 for constant buffers
  for (int t = 0; t < TILES_PER_SPLIT - 1; t += 3) {
    phase(VsB,        KsB + 4096, KsB + 8192, VsB + 8192, t + 2 < TILES_PER_SPLIT);
    phase(VsB + 4096, KsB + 8192, KsB,        VsB,        t + 3 < TILES_PER_SPLIT);
    phase(VsB + 8192, KsB,        KsB + 4096, VsB + 4096, t + 4 < TILES_PER_SPLIT);
  }

  // final PV: tile 15 lives in buf 15%3 = 0
  {
    union { unsigned u[4]; bf16x8 v; } pf0, pf1;
#if __has_builtin(__builtin_amdgcn_permlane32_swap)
    auto a0 = __builtin_amdgcn_permlane32_swap(w[0], w[2], false, false);
    auto a1 = __builtin_amdgcn_permlane32_swap(w[1], w[3], false, false);
    auto a2 = __builtin_amdgcn_permlane32_swap(w[4], w[6], false, false);
    auto a3 = __builtin_amdgcn_permlane32_swap(w[5], w[7], false, false);
    pf0.u[0] = a0[0]; pf0.u[1] = a1[0]; pf0.u[2] = a0[1]; pf0.u[3] = a1[1];
    pf1.u[0] = a2[0]; pf1.u[1] = a3[0]; pf1.u[2] = a2[1]; pf1.u[3] = a3[1];
#else
    unsigned t0 = hi ? w[0] : w[2], t1 = hi ? w[1] : w[3];
    unsigned t2 = hi ? w[4] : w[6], t3 = hi ? w[5] : w[7];
    unsigned r0 = __shfl_xor(t0, 32), r1 = __shfl_xor(t1, 32);
    unsigned r2 = __shfl_xor(t2, 32), r3 = __shfl_xor(t3, 32);
    pf0.u[0] = hi ? r0 : w[0]; pf0.u[1] = hi ? r1 : w[1];
    pf0.u[2] = hi ? w[2] : r0; pf0.u[3] = hi ? w[3] : r1;
    pf1.u[0] = hi ? r2 : w[4]; pf1.u[1] = hi ? r3 : w[5];
    pf1.u[2] = hi ? w[6] : r2; pf1.u[3] = hi ? w[7] : r3;
#endif
#pragma unroll
    for (int dm = 0; dm < 2; ++dm) {
      int vrow = dm * 32 + l31;
      bf16x8 vf0 = *(const bf16x8*)(VsB + vrow * 64 + ((kq * 32 + hi * 8) ^ ((vrow & 7) * 8)));
      osum[dm] = __builtin_amdgcn_mfma_f32_32x32x16_bf16(vf0, pf0.v, osum[dm], 0, 0, 0);
      bf16x8 vf1 = *(const bf16x8*)(VsB + vrow * 64 + ((kq * 32 + 16 + hi * 8) ^ ((vrow & 7) * 8)));
      osum[dm] = __builtin_amdgcn_mfma_f32_32x32x16_bf16(vf1, pf1.v, osum[dm], 0, 0, 0);
    }
  }

  // full per-q row sum for this wave's kq half
  lsum += __shfl_xor(lsum, 32);

  // ---- combine the 2 kq halves in LDS; write bf16 O-partial + f32 l-partial ----
  __syncthreads();                          // K/V tiles dead; arena reused
  float* bufA = (float*)arena;              // [4 rh][64 d][33 q] = 33792 B
#define OD(dm, r) ((dm) * 32 + ((r) & 3) + 8 * ((r) >> 2) + 4 * hi)
#define OADDR(dm, r) (rh * 2112 + OD(dm, r) * 33 + l31)
  if (kq == 1) {
    if (hi == 0) lzp[rh][l31] = lsum;
#pragma unroll
    for (int dm = 0; dm < 2; ++dm)
#pragma unroll
      for (int r = 0; r < 16; ++r) bufA[OADDR(dm, r)] = osum[dm][r];
  }
  __syncthreads();
  if (kq == 0) {
#pragma unroll
    for (int dm = 0; dm < 2; ++dm)
#pragma unroll
      for (int r = 0; r < 16; ++r) {
        float v = osum[dm][r] + bufA[OADDR(dm, r)];
        bufA[OADDR(dm, r)] = v;
      }
    float lt = lsum + lzp[rh][l31];
    if (hi == 0)
      lpart[(size_t)(split * NHEAD + h) * SEQ + q0 + rh * 32 + l31] = lt;
  }
  __syncthreads();
#undef OD
#undef OADDR

  // cooperative partial write: thread -> (q row, 16-d chunk)
  {
    int q_ = tid >> 2;             // 0..127
    int dc = (tid & 3) * 16;
    int qr = q_ >> 5, ql = q_ & 31;
    short ov[16];
#pragma unroll
    for (int i = 0; i < 16; ++i)
      ov[i] = f2b(bufA[qr * 2112 + (dc + i) * 33 + ql]);
    *(bf16x8*)(Opart + (size_t)(q0 + q_) * CDIM + h * 64 + dc) = *(bf16x8*)(ov);
    *(bf16x8*)(Opart + (size_t)(q0 + q_) * CDIM + h * 64 + dc + 8) = *(bf16x8*)(ov + 8);
  }
}

// ---- combine 4 kv-split partials: Ab = (sum O_s) / (sum l_s) ----
__global__ __launch_bounds__(256) void combine_kernel(
    const short* __restrict__ p0, const short* __restrict__ p1,
    const short* __restrict__ p2, const short* __restrict__ p3,
    const float* __restrict__ lpart, short* __restrict__ Ab) {
  int t = blockIdx.x * 256 + threadIdx.x;
  size_t base = (size_t)t * 8;
  int q = (int)(base >> 9), c = (int)(base & 511), h = c >> 6;
  float l = lpart[(size_t)(0 * NHEAD + h) * SEQ + q] +
            lpart[(size_t)(1 * NHEAD + h) * SEQ + q] +
            lpart[(size_t)(2 * NHEAD + h) * SEQ + q] +
            lpart[(size_t)(3 * NHEAD + h) * SEQ + q];
  float rinv = 1.f / l;
  bf16x8 a0 = *(const bf16x8*)(p0 + base);
  bf16x8 a1 = *(const bf16x8*)(p1 + base);
  bf16x8 a2 = *(const bf16x8*)(p2 + base);
  bf16x8 a3 = *(const bf16x8*)(p3 + base);
  short ov[8];
#pragma unroll
  for (int i = 0; i < 8; ++i)
    ov[i] = f2b((b2f(a0[i]) + b2f(a1[i]) + b2f(a2[i]) + b2f(a3[i])) * rinv);
  *(bf16x8*)(Ab + base) = *(bf16x8*)(ov);
}

extern "C" void kernel_launch(void* const* d_in, const int* in_sizes, int n_in,
                              void* d_out, int out_size, void* d_ws, size_t ws_size,
                              hipStream_t stream) {
  const float* x  = (const float*)d_in[0];
  const float* Wq = (const float*)d_in[1];
  const float* bq = (const float*)d_in[2];
  const float* Wk = (const float*)d_in[3];
  const float* bk = (const float*)d_in[4];
  const float* Wv = (const float*)d_in[5];
  const float* bv = (const float*)d_in[6];
  const float* Wo = (const float*)d_in[7];
  const float* bo = (const float*)d_in[8];
  float* out = (float*)d_out;

  short* ws = (short*)d_ws;
  size_t off = 0;
  short* xb  = ws + off; off += (size_t)SEQ * CDIM;   // reused as O-partial 0
  short* Wqt = ws + off; off += (size_t)CDIM * CDIM;
  short* Wkt = ws + off; off += (size_t)CDIM * CDIM;
  short* Wvt = ws + off; off += (size_t)CDIM * CDIM;
  short* Wot = ws + off; off += (size_t)CDIM * CDIM;
  short* Qb  = ws + off; off += (size_t)SEQ * CDIM;
  short* Kb  = ws + off; off += (size_t)SEQ * CDIM;
  short* Vtb = ws + off; off += (size_t)CDIM * SEQ;
  short* Ab  = ws + off; off += (size_t)SEQ * CDIM;
  short* Op1 = ws + off; off += (size_t)SEQ * CDIM;
  short* Op2 = ws + off; off += (size_t)SEQ * CDIM;
  short* Op3 = ws + off; off += (size_t)SEQ * CDIM;
  float* lpart = (float*)(ws + off); off += (size_t)NSPLIT * NHEAD * SEQ * 2;
  short* Op0 = xb;   // xb is dead after qkv_gemm

  prep_kernel<<<2048 + 4 * 256, 256, 0, stream>>>(x, Wq, Wk, Wv, Wo, xb, Wqt, Wkt, Wvt, Wot);
  qkv_gemm_kernel<<<dim3(SEQ / 64, CDIM / 64, 3), 256, 0, stream>>>(
      xb, Wqt, Wkt, Wvt, bq, bk, bv, Qb, Kb, Vtb);
  attn_kernel<<<(SEQ / 128) * NHEAD * NSPLIT, 512, 0, stream>>>(
      Qb, Kb, Vtb, Op0, Op1, Op2, Op3, lpart);
  combine_kernel<<<SEQ * CDIM / 8 / 256, 256, 0, stream>>>(Op0, Op1, Op2, Op3, lpart, Ab);
  out_gemm_kernel<<<dim3(SEQ / 64, CDIM / 64), 256, 0, stream>>>(Ab, Wot, bo, out);
}

// Round 9
// 81.768 us; speedup vs baseline: 2.1544x; 1.0696x over previous
//
#include <hip/hip_runtime.h>
#include <hip/hip_bf16.h>

#define SEQ 4096
#define CDIM 512
#define NHEAD 8
#define HDIM 64
#define KVB 64
#define NSPLIT 4
#define TILES_PER_SPLIT (SEQ / KVB / NSPLIT)   // 16

typedef __attribute__((ext_vector_type(8))) short bf16x8;
typedef __attribute__((ext_vector_type(4))) float f32x4;
typedef __attribute__((ext_vector_type(16))) float f32x16;

__device__ __forceinline__ short f2b(float f) {
  union { float f; unsigned u; } v; v.f = f;
  unsigned u = v.u;
  unsigned r = u + 0x7fffu + ((u >> 16) & 1u);
  return (short)(r >> 16);
}
__device__ __forceinline__ float b2f(short s) {
  union { unsigned u; float f; } v; v.u = ((unsigned)(unsigned short)s) << 16;
  return v.f;
}
__device__ __forceinline__ unsigned pk2(float a, float b) {
  union { __hip_bfloat162 h; unsigned u; } z;
  z.h = __float22bfloat162_rn(make_float2(a, b));
  return z.u;
}

// ---- prep: fp32->bf16 convert of x (blocks 0..2047) + 4 weight transposes ----
__global__ __launch_bounds__(256) void prep_kernel(
    const float* __restrict__ x,
    const float* __restrict__ Wq, const float* __restrict__ Wk,
    const float* __restrict__ Wv, const float* __restrict__ Wo,
    short* __restrict__ xb,
    short* __restrict__ Wqt, short* __restrict__ Wkt,
    short* __restrict__ Wvt, short* __restrict__ Wot) {
  __shared__ short tile[32][33];
  int b = blockIdx.x, tid = threadIdx.x;
  if (b < 2048) {
    int i = (b * 256 + tid) * 4;
    float4 v = *(const float4*)(x + i);
    short4 o;
    o.x = f2b(v.x); o.y = f2b(v.y); o.z = f2b(v.z); o.w = f2b(v.w);
    *(short4*)(xb + i) = o;
    return;
  }
  int t = b - 2048;
  int mat = t >> 8; t &= 255;
  const float* W = mat == 0 ? Wq : mat == 1 ? Wk : mat == 2 ? Wv : Wo;
  short* Wt = mat == 0 ? Wqt : mat == 1 ? Wkt : mat == 2 ? Wvt : Wot;
  int n0 = (t & 15) * 32, k0 = (t >> 4) * 32;
  int tx = tid & 31, ty = tid >> 5;  // 32 x 8
  for (int i = 0; i < 32; i += 8)
    tile[ty + i][tx] = f2b(W[(size_t)(k0 + ty + i) * CDIM + n0 + tx]);
  __syncthreads();
  for (int i = 0; i < 32; i += 8)
    Wt[(size_t)(n0 + ty + i) * CDIM + k0 + tx] = tile[tx][ty + i];
}

// ---- m97-style 128x64-tile GEMM core: C[128m x 64n] += A[128 x K] Bt[64 x K]^T
// 256 threads = 4 waves (2 row-halves x 2 col-halves), 32x32x16 MFMA frags,
// glds width-16 staging into swizzled LDS, single buffer + 2 barriers/K-step.
// Fragment convention (proven by attn PV R5-R8): A-operand lane l31 = A row;
// B-operand lane l31 = out col; D reg r row-offset f(r,hi) = (r&3)+8*(r>>2)+4*hi.
#define GEMM128_CORE(Asrc, Btsrc)                                                          \
  f32x16 acc[2] = {};                                                                      \
  const int tid = threadIdx.x;                                                             \
  const int wid = tid >> 6, lane = tid & 63, l31 = lane & 31, hi = lane >> 5;              \
  const int wr = wid >> 1, wc = wid & 1;                                                   \
  for (int kt = 0; kt < CDIM; kt += 64) {                                                  \
    __syncthreads();                                                                       \
    _Pragma("unroll")                                                                      \
    for (int i = 0; i < 4; ++i) {                                                          \
      int idx = i * 256 + tid, row = idx >> 3, seg = idx & 7;                              \
      int sc = (seg ^ (row & 7)) * 8;                                                      \
      __builtin_amdgcn_global_load_lds(                                                    \
          (const __attribute__((address_space(1))) void*)(Asrc + (size_t)(m0 + row) * CDIM + kt + sc), \
          (__attribute__((address_space(3))) void*)(As + idx * 8), 16, 0, 0);              \
    }                                                                                      \
    _Pragma("unroll")                                                                      \
    for (int i = 0; i < 2; ++i) {                                                          \
      int idx = i * 256 + tid, row = idx >> 3, seg = idx & 7;                              \
      int sc = (seg ^ (row & 7)) * 8;                                                      \
      __builtin_amdgcn_global_load_lds(                                                    \
          (const __attribute__((address_space(1))) void*)(Btsrc + (size_t)(n0 + row) * CDIM + kt + sc), \
          (__attribute__((address_space(3))) void*)(Bs + idx * 8), 16, 0, 0);              \
    }                                                                                      \
    __syncthreads();                                                                       \
    _Pragma("unroll")                                                                      \
    for (int ks = 0; ks < 4; ++ks) {                                                       \
      int brow = wc * 32 + l31;                                                            \
      bf16x8 bfr = *(const bf16x8*)(Bs + brow * 64 + ((ks * 16 + hi * 8) ^ ((brow & 7) * 8))); \
      _Pragma("unroll")                                                                    \
      for (int ai = 0; ai < 2; ++ai) {                                                     \
        int arow = wr * 64 + ai * 32 + l31;                                                \
        bf16x8 afr = *(const bf16x8*)(As + arow * 64 + ((ks * 16 + hi * 8) ^ ((arow & 7) * 8))); \
        acc[ai] = __builtin_amdgcn_mfma_f32_32x32x16_bf16(afr, bfr, acc[ai], 0, 0, 0);     \
      }                                                                                    \
    }                                                                                      \
  }

// ---- fused QKV GEMM (128x64 tiles): z=0 Qb, z=1 Kb (bf16 [M][N]); z=2 Vtb ([N][M]) ----
__global__ __launch_bounds__(256) void qkv128_kernel(
    const short* __restrict__ A,
    const short* __restrict__ Wqt, const short* __restrict__ Wkt, const short* __restrict__ Wvt,
    const float* __restrict__ bq, const float* __restrict__ bk, const float* __restrict__ bv,
    short* __restrict__ Qb, short* __restrict__ Kb, short* __restrict__ Vtb) {
  __shared__ __align__(16) short As[128 * 64];
  __shared__ __align__(16) short Bs[64 * 64];
  const int z = blockIdx.z;
  const short* Bt = z == 0 ? Wqt : z == 1 ? Wkt : Wvt;
  const float* bias = z == 0 ? bq : z == 1 ? bk : bv;
  const int m0 = blockIdx.x * 128, n0 = blockIdx.y * 64;
  GEMM128_CORE(A, Bt)
  const int ncol = n0 + wc * 32 + l31;
  const float bn = bias[ncol];
  if (z != 2) {
    short* D = z == 0 ? Qb : Kb;
#pragma unroll
    for (int ai = 0; ai < 2; ++ai)
#pragma unroll
      for (int r = 0; r < 16; ++r) {
        int m = m0 + wr * 64 + ai * 32 + (r & 3) + 8 * (r >> 2) + 4 * hi;
        D[(size_t)m * CDIM + ncol] = f2b(acc[ai][r] + bn);
      }
  } else {
#pragma unroll
    for (int ai = 0; ai < 2; ++ai)
#pragma unroll
      for (int r = 0; r < 16; ++r) {
        int m = m0 + wr * 64 + ai * 32 + (r & 3) + 8 * (r >> 2) + 4 * hi;
        Vtb[(size_t)ncol * SEQ + m] = f2b(acc[ai][r] + bn);
      }
  }
}

// ---- output projection GEMM (128x64 tiles): fp32 out + bias ----
__global__ __launch_bounds__(256) void out128_kernel(
    const short* __restrict__ A, const short* __restrict__ Bt,
    const float* __restrict__ bias, float* __restrict__ out) {
  __shared__ __align__(16) short As[128 * 64];
  __shared__ __align__(16) short Bs[64 * 64];
  const int m0 = blockIdx.x * 128, n0 = blockIdx.y * 64;
  GEMM128_CORE(A, Bt)
  const int ncol = n0 + wc * 32 + l31;
  const float bn = bias[ncol];
#pragma unroll
  for (int ai = 0; ai < 2; ++ai)
#pragma unroll
    for (int r = 0; r < 16; ++r) {
      int m = m0 + wr * 64 + ai * 32 + (r & 3) + 8 * (r >> 2) + 4 * hi;
      out[(size_t)m * CDIM + ncol] = acc[ai][r] + bn;
    }
}

// ---- flash attention partials, 1-tile-ahead software pipeline (unchanged R8). ----
__global__ __launch_bounds__(512, 4) void attn_kernel(
    const short* __restrict__ Qb,   // [SEQ][CDIM] bf16
    const short* __restrict__ Kb,   // [SEQ][CDIM] bf16
    const short* __restrict__ Vtb,  // [CDIM][SEQ] bf16 (d-major)
    short* __restrict__ Op0, short* __restrict__ Op1,
    short* __restrict__ Op2, short* __restrict__ Op3,
    float* __restrict__ lpart) {    // [NSPLIT][NHEAD][SEQ]
  __shared__ __align__(16) char arena[49152];   // K 3x8KB + V 3x8KB; epi: bufA[4][64][33] f32
  __shared__ float lzp[4][32];
  short* KsB = (short*)arena;                   // KsB + b*4096
  short* VsB = (short*)(arena + 24576);         // VsB + b*4096
  const int bid = blockIdx.x;
  const int h = bid & 7;                 // head ~ XCD
  const int rest = bid >> 3;
  const int split = rest & 3;
  const int q0 = (rest >> 2) * 128;
  const int kvbase = split * (TILES_PER_SPLIT * KVB);
  const int tid = threadIdx.x;
  const int wid = tid >> 6, lane = tid & 63;
  const int l31 = lane & 31, hi = lane >> 5;
  const int rh = wid >> 1, kq = wid & 1;
  const float scale2 = 0.06375872274f;   // (1/sqrt(512)) * log2(e)

  short* Opart = split == 0 ? Op0 : split == 1 ? Op1 : split == 2 ? Op2 : Op3;

  // Q in B-frag layout (n=q=lane&31, k-slices of d), pre-scaled
  bf16x8 qf[4];
  {
    int qrow = q0 + rh * 32 + l31;
#pragma unroll
    for (int kst = 0; kst < 4; ++kst) {
      bf16x8 q = *(const bf16x8*)(Qb + (size_t)qrow * CDIM + h * 64 + kst * 16 + hi * 8);
#pragma unroll
      for (int i = 0; i < 8; ++i) q[i] = f2b(b2f(q[i]) * scale2);
      qf[kst] = q;
    }
  }

  // glds staging pointers, strength-reduced: advance by constant per stage
  const int srow = tid >> 3;                       // 0..63 (K: kv row; V: d row)
  const int scol8 = 8 * ((tid & 7) ^ (srow & 7));  // inverse-swizzled source col
  const short* kstage = Kb + (size_t)(kvbase + srow) * CDIM + h * 64 + scol8;
  const short* vstage = Vtb + (size_t)(h * 64 + srow) * SEQ + kvbase + scol8;
  auto stage = [&](short* sK, short* sV) {
    __builtin_amdgcn_global_load_lds(
        (const __attribute__((address_space(1))) void*)kstage,
        (__attribute__((address_space(3))) void*)(sK + tid * 8), 16, 0, 0);
    __builtin_amdgcn_global_load_lds(
        (const __attribute__((address_space(1))) void*)vstage,
        (__attribute__((address_space(3))) void*)(sV + tid * 8), 16, 0, 0);
    kstage += KVB * CDIM;
    vstage += KVB;
  };

  f32x16 osum[2] = {};   // dm=0,1 : O^T[d = dm*32 + frag][q]
  float lsum = 0.f;
  unsigned w[8];         // carried P (bf16x2 pairs) for the PV of the previous tile

  auto softmax = [&](f32x16& s) {
    float ls0 = 0.f, ls1 = 0.f;
#pragma unroll
    for (int m = 0; m < 8; ++m) {
      float p0 = __builtin_amdgcn_exp2f(s[2 * m]);
      float p1 = __builtin_amdgcn_exp2f(s[2 * m + 1]);
      ls0 += p0; ls1 += p1;
      w[m] = pk2(p0, p1);
    }
    lsum += ls0 + ls1;
  };

  auto phase = [&](const short* vbuf, const short* kbuf, short* sK, short* sV, bool do_st) {
    if (do_st) stage(sK, sV);
    union { unsigned u[4]; bf16x8 v; } pf0, pf1;
#if __has_builtin(__builtin_amdgcn_permlane32_swap)
    {
      auto a0 = __builtin_amdgcn_permlane32_swap(w[0], w[2], false, false);
      auto a1 = __builtin_amdgcn_permlane32_swap(w[1], w[3], false, false);
      auto a2 = __builtin_amdgcn_permlane32_swap(w[4], w[6], false, false);
      auto a3 = __builtin_amdgcn_permlane32_swap(w[5], w[7], false, false);
      pf0.u[0] = a0[0]; pf0.u[1] = a1[0]; pf0.u[2] = a0[1]; pf0.u[3] = a1[1];
      pf1.u[0] = a2[0]; pf1.u[1] = a3[0]; pf1.u[2] = a2[1]; pf1.u[3] = a3[1];
    }
#else
    {
      unsigned t0 = hi ? w[0] : w[2], t1 = hi ? w[1] : w[3];
      unsigned t2 = hi ? w[4] : w[6], t3 = hi ? w[5] : w[7];
      unsigned r0 = __shfl_xor(t0, 32), r1 = __shfl_xor(t1, 32);
      unsigned r2 = __shfl_xor(t2, 32), r3 = __shfl_xor(t3, 32);
      pf0.u[0] = hi ? r0 : w[0]; pf0.u[1] = hi ? r1 : w[1];
      pf0.u[2] = hi ? w[2] : r0; pf0.u[3] = hi ? w[3] : r1;
      pf1.u[0] = hi ? r2 : w[4]; pf1.u[1] = hi ? r3 : w[5];
      pf1.u[2] = hi ? w[6] : r2; pf1.u[3] = hi ? w[7] : r3;
    }
#endif
    f32x16 s = {};
    __builtin_amdgcn_s_setprio(1);
#pragma unroll
    for (int kst = 0; kst < 4; ++kst) {
      int row = kq * 32 + l31;
      bf16x8 kf = *(const bf16x8*)(kbuf + row * 64 + ((kst * 16 + hi * 8) ^ ((row & 7) * 8)));
      s = __builtin_amdgcn_mfma_f32_32x32x16_bf16(kf, qf[kst], s, 0, 0, 0);
    }
#pragma unroll
    for (int dm = 0; dm < 2; ++dm) {
      int vrow = dm * 32 + l31;
      bf16x8 vf0 = *(const bf16x8*)(vbuf + vrow * 64 + ((kq * 32 + hi * 8) ^ ((vrow & 7) * 8)));
      osum[dm] = __builtin_amdgcn_mfma_f32_32x32x16_bf16(vf0, pf0.v, osum[dm], 0, 0, 0);
      bf16x8 vf1 = *(const bf16x8*)(vbuf + vrow * 64 + ((kq * 32 + 16 + hi * 8) ^ ((vrow & 7) * 8)));
      osum[dm] = __builtin_amdgcn_mfma_f32_32x32x16_bf16(vf1, pf1.v, osum[dm], 0, 0, 0);
    }
    __builtin_amdgcn_s_setprio(0);
    softmax(s);
    __syncthreads();
  };

  // prologue: tiles 0 and 1
  stage(KsB, VsB);
  __syncthreads();
  stage(KsB + 4096, VsB + 4096);
  {
    f32x16 s = {};
#pragma unroll
    for (int kst = 0; kst < 4; ++kst) {
      int row = kq * 32 + l31;
      bf16x8 kf = *(const bf16x8*)(KsB + row * 64 + ((kst * 16 + hi * 8) ^ ((row & 7) * 8)));
      s = __builtin_amdgcn_mfma_f32_32x32x16_bf16(kf, qf[kst], s, 0, 0, 0);
    }
    softmax(s);
  }
  __syncthreads();

  for (int t = 0; t < TILES_PER_SPLIT - 1; t += 3) {
    phase(VsB,        KsB + 4096, KsB + 8192, VsB + 8192, t + 2 < TILES_PER_SPLIT);
    phase(VsB + 4096, KsB + 8192, KsB,        VsB,        t + 3 < TILES_PER_SPLIT);
    phase(VsB + 8192, KsB,        KsB + 4096, VsB + 4096, t + 4 < TILES_PER_SPLIT);
  }

  // final PV: tile 15 lives in buf 0
  {
    union { unsigned u[4]; bf16x8 v; } pf0, pf1;
#if __has_builtin(__builtin_amdgcn_permlane32_swap)
    auto a0 = __builtin_amdgcn_permlane32_swap(w[0], w[2], false, false);
    auto a1 = __builtin_amdgcn_permlane32_swap(w[1], w[3], false, false);
    auto a2 = __builtin_amdgcn_permlane32_swap(w[4], w[6], false, false);
    auto a3 = __builtin_amdgcn_permlane32_swap(w[5], w[7], false, false);
    pf0.u[0] = a0[0]; pf0.u[1] = a1[0]; pf0.u[2] = a0[1]; pf0.u[3] = a1[1];
    pf1.u[0] = a2[0]; pf1.u[1] = a3[0]; pf1.u[2] = a2[1]; pf1.u[3] = a3[1];
#else
    unsigned t0 = hi ? w[0] : w[2], t1 = hi ? w[1] : w[3];
    unsigned t2 = hi ? w[4] : w[6], t3 = hi ? w[5] : w[7];
    unsigned r0 = __shfl_xor(t0, 32), r1 = __shfl_xor(t1, 32);
    unsigned r2 = __shfl_xor(t2, 32), r3 = __shfl_xor(t3, 32);
    pf0.u[0] = hi ? r0 : w[0]; pf0.u[1] = hi ? r1 : w[1];
    pf0.u[2] = hi ? w[2] : r0; pf0.u[3] = hi ? w[3] : r1;
    pf1.u[0] = hi ? r2 : w[4]; pf1.u[1] = hi ? r3 : w[5];
    pf1.u[2] = hi ? w[6] : r2; pf1.u[3] = hi ? w[7] : r3;
#endif
#pragma unroll
    for (int dm = 0; dm < 2; ++dm) {
      int vrow = dm * 32 + l31;
      bf16x8 vf0 = *(const bf16x8*)(VsB + vrow * 64 + ((kq * 32 + hi * 8) ^ ((vrow & 7) * 8)));
      osum[dm] = __builtin_amdgcn_mfma_f32_32x32x16_bf16(vf0, pf0.v, osum[dm], 0, 0, 0);
      bf16x8 vf1 = *(const bf16x8*)(VsB + vrow * 64 + ((kq * 32 + 16 + hi * 8) ^ ((vrow & 7) * 8)));
      osum[dm] = __builtin_amdgcn_mfma_f32_32x32x16_bf16(vf1, pf1.v, osum[dm], 0, 0, 0);
    }
  }

  lsum += __shfl_xor(lsum, 32);

  __syncthreads();
  float* bufA = (float*)arena;              // [4 rh][64 d][33 q]
#define OD(dm, r) ((dm) * 32 + ((r) & 3) + 8 * ((r) >> 2) + 4 * hi)
#define OADDR(dm, r) (rh * 2112 + OD(dm, r) * 33 + l31)
  if (kq == 1) {
    if (hi == 0) lzp[rh][l31] = lsum;
#pragma unroll
    for (int dm = 0; dm < 2; ++dm)
#pragma unroll
      for (int r = 0; r < 16; ++r) bufA[OADDR(dm, r)] = osum[dm][r];
  }
  __syncthreads();
  if (kq == 0) {
#pragma unroll
    for (int dm = 0; dm < 2; ++dm)
#pragma unroll
      for (int r = 0; r < 16; ++r) {
        float v = osum[dm][r] + bufA[OADDR(dm, r)];
        bufA[OADDR(dm, r)] = v;
      }
    float lt = lsum + lzp[rh][l31];
    if (hi == 0)
      lpart[(size_t)(split * NHEAD + h) * SEQ + q0 + rh * 32 + l31] = lt;
  }
  __syncthreads();
#undef OD
#undef OADDR

  {
    int q_ = tid >> 2;             // 0..127
    int dc = (tid & 3) * 16;
    int qr = q_ >> 5, ql = q_ & 31;
    short ov[16];
#pragma unroll
    for (int i = 0; i < 16; ++i)
      ov[i] = f2b(bufA[qr * 2112 + (dc + i) * 33 + ql]);
    *(bf16x8*)(Opart + (size_t)(q0 + q_) * CDIM + h * 64 + dc) = *(bf16x8*)(ov);
    *(bf16x8*)(Opart + (size_t)(q0 + q_) * CDIM + h * 64 + dc + 8) = *(bf16x8*)(ov + 8);
  }
}

// ---- combine 4 kv-split partials: Ab = (sum O_s) / (sum l_s) ----
__global__ __launch_bounds__(256) void combine_kernel(
    const short* __restrict__ p0, const short* __restrict__ p1,
    const short* __restrict__ p2, const short* __restrict__ p3,
    const float* __restrict__ lpart, short* __restrict__ Ab) {
  int t = blockIdx.x * 256 + threadIdx.x;
  size_t base = (size_t)t * 8;
  int q = (int)(base >> 9), c = (int)(base & 511), h = c >> 6;
  float l = lpart[(size_t)(0 * NHEAD + h) * SEQ + q] +
            lpart[(size_t)(1 * NHEAD + h) * SEQ + q] +
            lpart[(size_t)(2 * NHEAD + h) * SEQ + q] +
            lpart[(size_t)(3 * NHEAD + h) * SEQ + q];
  float rinv = 1.f / l;
  bf16x8 a0 = *(const bf16x8*)(p0 + base);
  bf16x8 a1 = *(const bf16x8*)(p1 + base);
  bf16x8 a2 = *(const bf16x8*)(p2 + base);
  bf16x8 a3 = *(const bf16x8*)(p3 + base);
  short ov[8];
#pragma unroll
  for (int i = 0; i < 8; ++i)
    ov[i] = f2b((b2f(a0[i]) + b2f(a1[i]) + b2f(a2[i]) + b2f(a3[i])) * rinv);
  *(bf16x8*)(Ab + base) = *(bf16x8*)(ov);
}

extern "C" void kernel_launch(void* const* d_in, const int* in_sizes, int n_in,
                              void* d_out, int out_size, void* d_ws, size_t ws_size,
                              hipStream_t stream) {
  const float* x  = (const float*)d_in[0];
  const float* Wq = (const float*)d_in[1];
  const float* bq = (const float*)d_in[2];
  const float* Wk = (const float*)d_in[3];
  const float* bk = (const float*)d_in[4];
  const float* Wv = (const float*)d_in[5];
  const float* bv = (const float*)d_in[6];
  const float* Wo = (const float*)d_in[7];
  const float* bo = (const float*)d_in[8];
  float* out = (float*)d_out;

  short* ws = (short*)d_ws;
  size_t off = 0;
  short* xb  = ws + off; off += (size_t)SEQ * CDIM;   // reused as O-partial 0
  short* Wqt = ws + off; off += (size_t)CDIM * CDIM;
  short* Wkt = ws + off; off += (size_t)CDIM * CDIM;
  short* Wvt = ws + off; off += (size_t)CDIM * CDIM;
  short* Wot = ws + off; off += (size_t)CDIM * CDIM;
  short* Qb  = ws + off; off += (size_t)SEQ * CDIM;
  short* Kb  = ws + off; off += (size_t)SEQ * CDIM;
  short* Vtb = ws + off; off += (size_t)CDIM * SEQ;
  short* Ab  = ws + off; off += (size_t)SEQ * CDIM;
  short* Op1 = ws + off; off += (size_t)SEQ * CDIM;
  short* Op2 = ws + off; off += (size_t)SEQ * CDIM;
  short* Op3 = ws + off; off += (size_t)SEQ * CDIM;
  float* lpart = (float*)(ws + off); off += (size_t)NSPLIT * NHEAD * SEQ * 2;
  short* Op0 = xb;   // xb is dead after qkv

  prep_kernel<<<2048 + 4 * 256, 256, 0, stream>>>(x, Wq, Wk, Wv, Wo, xb, Wqt, Wkt, Wvt, Wot);
  qkv128_kernel<<<dim3(SEQ / 128, CDIM / 64, 3), 256, 0, stream>>>(
      xb, Wqt, Wkt, Wvt, bq, bk, bv, Qb, Kb, Vtb);
  attn_kernel<<<(SEQ / 128) * NHEAD * NSPLIT, 512, 0, stream>>>(
      Qb, Kb, Vtb, Op0, Op1, Op2, Op3, lpart);
  combine_kernel<<<SEQ * CDIM / 8 / 256, 256, 0, stream>>>(Op0, Op1, Op2, Op3, lpart, Ab);
  out128_kernel<<<dim3(SEQ / 128, CDIM / 64), 256, 0, stream>>>(Ab, Wot, bo, out);
}